// Round 11
// baseline (23.899 us; speedup 1.0000x reference)
//
#include <hip/hip_runtime.h>

// Problem constants
#define B_IMG 8
#define C_IN  16
#define COUT  64
#define H0    36
#define H1    6
#define NB    6
#define NNODE 43
// OH=OW=16; output [8][64][16][16]

typedef float f32x2 __attribute__((ext_vector_type(2)));

__device__ __forceinline__ float sigf(float v) { return 1.0f / (1.0f + __expf(-v)); }
__device__ __forceinline__ float4 sig4(float4 a) {
    return make_float4(sigf(a.x), sigf(a.y), sigf(a.z), sigf(a.w));
}

// 6-bit multilinear interp, delta-form table in registers.
// g[0] contracts the MSB ... g[5] the LSB (matches reference einsum order).
__device__ __forceinline__ float lut_contract_reg(const float4 lo4[8], const float4 dd4[8],
                                                  const float g[NB]) {
    f32x2 v[16];
    const float g0 = g[0];
#pragma unroll
    for (int q = 0; q < 8; ++q) {
        v[2*q+0] = (f32x2){lo4[q].x, lo4[q].y} + (f32x2){dd4[q].x, dd4[q].y} * g0;
        v[2*q+1] = (f32x2){lo4[q].z, lo4[q].w} + (f32x2){dd4[q].z, dd4[q].w} * g0;
    }
#pragma unroll
    for (int i = 1; i < 5; ++i) {
        const int vh = 16 >> i;
        const float gi = g[i];
#pragma unroll
        for (int r = 0; r < vh; ++r)
            v[r] += (v[r + vh] - v[r]) * gi;
    }
    return v[0].x + (v[0].y - v[0].x) * g[5];
}

// Read a 64-entry delta table from LDS (wave-uniform addr -> broadcast reads).
__device__ __forceinline__ void load_tbl_lds(const float* tb, float4 lo4[8], float4 dd4[8]) {
    const float4* t4 = (const float4*)tb;
#pragma unroll
    for (int q = 0; q < 8; ++q) { lo4[q] = t4[q]; dd4[q] = t4[q + 8]; }
}

// Block = (channel t, image img, 128-px half): 256 threads = 4 waves.
// LDS ~34 KB -> 3-4 independent blocks co-resident per CU (vs 2 with 512-thr
// blocks): private barriers per block let phases overlap across blocks.
__global__ __launch_bounds__(256) void lutone_kernel(
    const float* __restrict__ x,
    const int*   __restrict__ idx0,
    const float* __restrict__ t0,
    const int*   __restrict__ idx1,
    const float* __restrict__ t1,
    const int*   __restrict__ idx2,
    const float* __restrict__ t2,
    float*       __restrict__ out)
{
    __shared__ float tblL[NNODE*64];   // sigmoid'd delta tables: lo[32]|dd[32]
    __shared__ float h0s[H0*128];      // [raw node][px] — bank = px, conflict-free
    __shared__ float h1s[H1*128];
    __shared__ int   metaL[H0*NB*2];   // per (node,i): {off, rem}
    __shared__ int   idx1L[H1*NB];
    __shared__ int   idx2L[NB];

    const int tid  = threadIdx.x;
    const int w    = tid >> 6;
    const int lane = tid & 63;
    const int b    = blockIdx.x;
    const int t    = b & 63;
    const int img  = (b >> 6) & 7;
    const int half = b >> 9;

    // ---- stage sigmoid'd delta tables into LDS (vectorized: 344 float4-pairs) ----
    {
        float4* tbl4 = (float4*)tblL;
        for (int e = tid; e < NNODE*8; e += 256) {
            const int node = e >> 3, q = e & 7;
            const float* src = (node < H0)      ? t0 + ((size_t)t*H0 + node)*64
                             : (node < H0+H1)   ? t1 + ((size_t)t*H1 + node - H0)*64
                                                : t2 + (size_t)t*64;
            const float4* s4 = (const float4*)src;
            const float4 lo = sig4(s4[q]);
            const float4 hi = sig4(s4[q + 8]);
            tbl4[node*16 + q]     = lo;
            tbl4[node*16 + 8 + q] = make_float4(hi.x - lo.x, hi.y - lo.y,
                                                hi.z - lo.z, hi.w - lo.w);
        }
    }
    // ---- decode idx0 -> LDS meta (one thread per (node,bit)) ----
    if (tid < H0*NB) {
        const int raw = idx0[(size_t)t*(H0*NB) + tid];
        const int c2  = raw / 25;
        const int rem = raw - 25*c2;                   // kh*5 + kw
        const int kh  = rem / 5, kw = rem - 5*kh;
        metaL[tid*2 + 0] = c2*1024 + kh*32 + kw - 66;  // -(2*32+2) halo shift
        metaL[tid*2 + 1] = rem;
    }
    if (tid < H1*NB) idx1L[tid] = idx1[(size_t)t*(H1*NB) + tid];
    if (tid < NB)    idx2L[tid] = idx2[(size_t)t*NB + tid];

    // ---- wave-uniform used-node mask (scalar pipe, overlaps staging) ----
    const int* i1base = idx1 + t*(H1*NB);
    unsigned long long umask = 0ull;
#pragma unroll
    for (int j = 0; j < H1*NB; ++j) umask |= 1ull << i1base[j];

    // ---- per-lane pixel geometry: 2 chunks (px = half*128 + c*64 + lane) ----
    int base[2], vmask[2];
#pragma unroll
    for (int c = 0; c < 2; ++c) {
        const int p  = half*128 + (c << 6) + lane;
        const int oh = p >> 4, ow = p & 15;
        base[c] = img*16384 + oh*64 + ow*2;            // oh2*32 + ow2
        const int hm = 0x1F ^ ((oh == 0) ? 0x03 : 0) ^ ((oh == 15) ? 0x10 : 0);
        const int wm = 0x1F ^ ((ow == 0) ? 0x03 : 0) ^ ((ow == 15) ? 0x10 : 0);
        int vm = 0;
#pragma unroll
        for (int kh = 0; kh < 5; ++kh)
            vm |= ((hm >> kh) & 1) ? (wm << (5*kh)) : 0;
        vmask[c] = vm;
    }

    // ---- this wave's node assignment (<=9 nodes, named regs: rule #20) ----
    int myn0=-1, myn1=-1, myn2=-1, myn3=-1, myn4=-1, myn5=-1, myn6=-1, myn7=-1, myn8=-1;
    {
        int cnt = 0;
        for (int n = 0; n < H0; ++n) {
            if (!((umask >> n) & 1ull)) continue;
            const int slot = cnt++;
            if ((slot & 3) != w) continue;
            switch (slot >> 2) {
                case 0: myn0 = n; break;
                case 1: myn1 = n; break;
                case 2: myn2 = n; break;
                case 3: myn3 = n; break;
                case 4: myn4 = n; break;
                case 5: myn5 = n; break;
                case 6: myn6 = n; break;
                case 7: myn7 = n; break;
                default: myn8 = n; break;
            }
        }
    }
    __syncthreads();

    // ---- phase A: layer 0; both chunks' gathers issued before contracting ----
#define GATH(dst, C)                                                         \
    _Pragma("unroll")                                                        \
    for (int i = 0; i < NB; ++i) {                                           \
        const bool ok = ((vmask[C] >> rem_[i]) & 1) != 0;                    \
        const float v = x[ok ? (base[C] + off_[i]) : 0];                     \
        dst[i] = ok ? v : 0.0f;                                              \
    }
#define NODE_A(NN)                                                           \
    if ((NN) >= 0) {                                                         \
        const int4* mp = (const int4*)(metaL + (NN)*12);                     \
        const int4 ma = mp[0], mb = mp[1], mc = mp[2];                       \
        const int off_[NB] = {ma.x, ma.z, mb.x, mb.z, mc.x, mc.z};           \
        const int rem_[NB] = {ma.y, ma.w, mb.y, mb.w, mc.y, mc.w};           \
        float gA[NB], gB[NB];                                                \
        GATH(gA, 0)                                                          \
        float4 lo4[8], dd4[8];                                               \
        load_tbl_lds(tblL + (NN)*64, lo4, dd4);                              \
        GATH(gB, 1)                                                          \
        h0s[(NN)*128 + lane]      = lut_contract_reg(lo4, dd4, gA);          \
        h0s[(NN)*128 + 64 + lane] = lut_contract_reg(lo4, dd4, gB);          \
    }
    NODE_A(myn0)
    NODE_A(myn1)
    NODE_A(myn2)
    NODE_A(myn3)
    NODE_A(myn4)
    NODE_A(myn5)
    NODE_A(myn6)
    NODE_A(myn7)
    NODE_A(myn8)
#undef NODE_A
#undef GATH
    __syncthreads();

    // ---- phase B: layer 1; 12 chunk-units (6 nodes x 2 chunks), 3 per wave ----
#pragma unroll
    for (int j = 0; j < 3; ++j) {
        const int u = 3*w + j;
        const int n = u >> 1, c = u & 1;
        float4 lo4[8], dd4[8];
        load_tbl_lds(tblL + (H0 + n)*64, lo4, dd4);
        const int* i1 = idx1L + n*NB;
        const int px = (c << 6) + lane;
        float g[NB];
#pragma unroll
        for (int i = 0; i < NB; ++i) g[i] = h0s[i1[i]*128 + px];
        h1s[n*128 + px] = lut_contract_reg(lo4, dd4, g);
    }
    __syncthreads();

    // ---- phase C: layer 2; 2 chunk-units on waves 0,1 ----
    if (w < 2) {
        float4 lo4[8], dd4[8];
        load_tbl_lds(tblL + (H0 + H1)*64, lo4, dd4);
        const int px = (w << 6) + lane;
        float g[NB];
#pragma unroll
        for (int i = 0; i < NB; ++i) g[i] = h1s[idx2L[i]*128 + px];
        out[((size_t)img*COUT + t)*256 + half*128 + px] = lut_contract_reg(lo4, dd4, g);
    }
}

extern "C" void kernel_launch(void* const* d_in, const int* in_sizes, int n_in,
                              void* d_out, int out_size, void* d_ws, size_t ws_size,
                              hipStream_t stream) {
    const float* x      = (const float*)d_in[0];
    const int*   idx0   = (const int*)  d_in[1];
    const float* table0 = (const float*)d_in[2];
    const int*   idx1   = (const int*)  d_in[3];
    const float* table1 = (const float*)d_in[4];
    const int*   idx2   = (const int*)  d_in[5];
    const float* table2 = (const float*)d_in[6];
    float* out = (float*)d_out;

    lutone_kernel<<<COUT * B_IMG * 2, 256, 0, stream>>>(
        x, idx0, table0, idx1, table1, idx2, table2, out);
}